// Round 17
// baseline (803.055 us; speedup 1.0000x reference)
//
#include <hip/hip_runtime.h>
#include <cstdint>
#include <cstddef>

#define N_NODES 8192
#define NFEAT   512
#define NHID    128

typedef unsigned short u16;
typedef __attribute__((ext_vector_type(8))) short bf16x8;
typedef __attribute__((ext_vector_type(4))) float f32x4;

__device__ inline u16 f2bf(float f) {
    unsigned int u = __float_as_uint(f);
    unsigned int r = (u + 0x7FFFu + ((u >> 16) & 1u)) >> 16;
    return (u16)r;
}
__device__ inline float bf2f(u16 h) {
    return __uint_as_float(((unsigned int)h) << 16);
}

// ---------------------------------------------------------------------------
// ROUND 17 = R16 baseline with attn_heads SPLIT into attn_k + heads_k
// (spill-avoidance: each standalone kernel has a small live set).
// Workspace layout (bytes): identical to R16.
//   [0]          bitmap    : 8388608
//   [8388608]    cnt       : 32768
//   [8421376]    rep_preh  : 4194304   (bf16 [N,256])
//   [12615680]   rep       : 8388608   (f32  [N,256])
//   [21004288]   rep_t_h   : 2097152   (bf16 [N,128])
//   [23101440]   u         : 32768
//   [23134208]   v         : 32768
//   [23166976]   rowptr    : 33280
//   [23200256]   colidx    : 1048576
//   [24248832]   colpart   : 2048*128*4 = 1048576
//   [25297408]   colpart2  : 64*128*4   = 32768
// ---------------------------------------------------------------------------

// ====== K1: blocks 0..511 GEMM (XCD-swizzled tiles), 512..2559 zero ws ======
__global__ __launch_bounds__(256)
void init_gemm(const float* __restrict__ x,
               const float* __restrict__ gcW,
               const float* __restrict__ gctW,
               u16* __restrict__ rep_preh,
               uint4* __restrict__ zdst, int n16)
{
    const int tid = threadIdx.x;
    if (blockIdx.x >= 512) {
        const uint4 z = make_uint4(0u, 0u, 0u, 0u);
        for (int i = (blockIdx.x - 512) * 256 + tid; i < n16; i += 2048 * 256)
            zdst[i] = z;
        return;
    }
    const int tile = (blockIdx.x & 7) * 64 + (blockIdx.x >> 3);  // XCD swizzle
    const int bx   = tile & 3;
    const int by   = tile >> 2;
    const int lane = tid & 63;
    const int wid  = tid >> 6;
    const int wr   = wid >> 1, wc = wid & 1;
    const float* W = (bx < 2) ? gcW : gctW;
    const int n0w  = (bx & 1) * 64;
    const int row0 = by * 64;

    __shared__ __align__(16) u16 Ash[64][40];
    __shared__ __align__(16) u16 Bsh[64][40];

    f32x4 acc[2][2];
#pragma unroll
    for (int i = 0; i < 2; ++i)
#pragma unroll
        for (int j = 0; j < 2; ++j) acc[i][j] = (f32x4){0.f, 0.f, 0.f, 0.f};

    const int sr = tid >> 2;
    const int sq = tid & 3;
    const int fr = lane & 15;
    const int fq = lane >> 4;

    for (int k0 = 0; k0 < NFEAT; k0 += 32) {
        {
            const float* src = x + (size_t)(row0 + sr) * NFEAT + k0 + sq * 8;
            const float4 a0 = *reinterpret_cast<const float4*>(src);
            const float4 a1 = *reinterpret_cast<const float4*>(src + 4);
            union { u16 s[8]; bf16x8 v; } pk;
            pk.s[0] = f2bf(a0.x); pk.s[1] = f2bf(a0.y);
            pk.s[2] = f2bf(a0.z); pk.s[3] = f2bf(a0.w);
            pk.s[4] = f2bf(a1.x); pk.s[5] = f2bf(a1.y);
            pk.s[6] = f2bf(a1.z); pk.s[7] = f2bf(a1.w);
            *reinterpret_cast<bf16x8*>(&Ash[sr][sq * 8]) = pk.v;
        }
        {
            const float* wsrc = W + (size_t)(k0 + sq * 8) * NHID + n0w + sr;
            union { u16 s[8]; bf16x8 v; } pk;
#pragma unroll
            for (int j = 0; j < 8; ++j)
                pk.s[j] = f2bf(wsrc[(size_t)j * NHID]);
            *reinterpret_cast<bf16x8*>(&Bsh[sr][sq * 8]) = pk.v;
        }
        __syncthreads();
        const bf16x8 a0 = *reinterpret_cast<const bf16x8*>(&Ash[wr * 32 + fr][fq * 8]);
        const bf16x8 a1 = *reinterpret_cast<const bf16x8*>(&Ash[wr * 32 + 16 + fr][fq * 8]);
        const bf16x8 b0 = *reinterpret_cast<const bf16x8*>(&Bsh[wc * 32 + fr][fq * 8]);
        const bf16x8 b1 = *reinterpret_cast<const bf16x8*>(&Bsh[wc * 32 + 16 + fr][fq * 8]);
        acc[0][0] = __builtin_amdgcn_mfma_f32_16x16x32_bf16(a0, b0, acc[0][0], 0, 0, 0);
        acc[0][1] = __builtin_amdgcn_mfma_f32_16x16x32_bf16(a0, b1, acc[0][1], 0, 0, 0);
        acc[1][0] = __builtin_amdgcn_mfma_f32_16x16x32_bf16(a1, b0, acc[1][0], 0, 0, 0);
        acc[1][1] = __builtin_amdgcn_mfma_f32_16x16x32_bf16(a1, b1, acc[1][1], 0, 0, 0);
        __syncthreads();
    }
    const int gr = row0 + wr * 32 + fq * 4;
    const int gc = bx * 64 + wc * 32 + fr;
#pragma unroll
    for (int mi = 0; mi < 2; ++mi)
#pragma unroll
        for (int ni = 0; ni < 2; ++ni)
#pragma unroll
            for (int i = 0; i < 4; ++i)
                rep_preh[(size_t)(gr + mi * 16 + i) * 256 + gc + ni * 16] =
                    f2bf(acc[mi][ni][i]);
}

// ============ K2: edge dedup (bitmap ownership + row counts) ================
__global__ void edge_pass1(const int* __restrict__ ei, int E,
                           unsigned int* __restrict__ bitmap,
                           int* __restrict__ cnt)
{
    const int e = blockIdx.x * blockDim.x + threadIdx.x;
    if (e >= E) return;
    const int s = ei[e];
    const int d = ei[E + e];
    const unsigned int idx  = (unsigned int)s * 8192u + (unsigned int)d;
    const unsigned int mask = 1u << (idx & 31u);
    const unsigned int old  = atomicOr(&bitmap[idx >> 5], mask);
    if ((old & mask) == 0u) atomicAdd(&cnt[s], 1);  // int add: deterministic
}

// ====== K3: fused {base-offset, extract, aggregate, u/v, colsum partials}
//        2048 blocks x 256 thr; wave w owns row 4b+w; lane owns 4 feats. ====
__global__ __launch_bounds__(256)
void agg_all(const unsigned int* __restrict__ bitmap,
             const int* __restrict__ cnt,
             const u16* __restrict__ rep_preh,
             const float* __restrict__ gcB,
             const float* __restrict__ gctB,
             const float* __restrict__ avec,
             int* __restrict__ rowptr,
             int* __restrict__ colidx,
             float* __restrict__ rep,
             u16* __restrict__ rep_t_h,
             float* __restrict__ u,
             float* __restrict__ v,
             float* __restrict__ colpart)   // [2048][128]
{
    const int b   = blockIdx.x;
    const int tid = threadIdx.x;
    const int w   = tid >> 6, ln = tid & 63;
    const int R0  = b * 4;

    __shared__ int   red_i[256];
    __shared__ int   rowoff[5];
    __shared__ float scs[4][128];

    // ---- base offset = sum cnt[0 .. R0) ------------------------------------
    {
        int ssum = 0;
        const int cb = tid * 32;
        if (cb + 32 <= R0) {
#pragma unroll
            for (int j = 0; j < 32; ++j) ssum += cnt[cb + j];
        } else if (cb < R0) {
            const int lim = R0 - cb;
            for (int j = 0; j < lim; ++j) ssum += cnt[cb + j];
        }
        red_i[tid] = ssum;
        __syncthreads();
#pragma unroll
        for (int s = 128; s > 0; s >>= 1) {
            if (tid < s) red_i[tid] += red_i[tid + s];
            __syncthreads();
        }
        if (tid == 0) {
            int off = red_i[0];
            for (int j = 0; j < 4; ++j) {
                rowoff[j] = off;
                rowptr[R0 + j] = off;
                off += cnt[R0 + j];
            }
            rowoff[4] = off;
            if (b == 2047) rowptr[N_NODES] = off;
        }
        __syncthreads();
    }

    // ---- extract sorted cols: wave w does row R0+w -------------------------
    {
        const int row = R0 + w;
        const uint4 w4 = *reinterpret_cast<const uint4*>(
            bitmap + (size_t)row * 256 + ln * 4);
        const int c = __popc(w4.x) + __popc(w4.y) + __popc(w4.z) + __popc(w4.w);
        int off = c;
        for (int d = 1; d < 64; d <<= 1) {
            const int n = __shfl_up(off, d, 64);
            if (ln >= d) off += n;
        }
        off -= c;
        int pos = rowoff[w] + off;
        const int base = ln * 128;
        unsigned int wvv[4] = {w4.x, w4.y, w4.z, w4.w};
#pragma unroll
        for (int j = 0; j < 4; ++j) {
            unsigned int bb = wvv[j];
            while (bb) {
                const int bit = __ffs(bb) - 1;
                colidx[pos++] = base + j * 32 + bit;
                bb &= bb - 1;
            }
        }
    }
    __syncthreads();

    // ---- aggregate row R0+w: lane ln owns feats ln*4..ln*4+3 ---------------
    const int i   = R0 + w;
    const int rp  = rowoff[w];
    const int rpe = rowoff[w + 1];

    float ax[4][4];
#pragma unroll
    for (int d = 0; d < 4; ++d)
#pragma unroll
        for (int j = 0; j < 4; ++j) ax[d][j] = 0.f;

    int q = rp;
    for (; q + 4 <= rpe; q += 4) {
#pragma unroll
        for (int d = 0; d < 4; ++d) {
            const int c = colidx[q + d];
            const uint2 pk = *reinterpret_cast<const uint2*>(
                rep_preh + (size_t)c * 256 + ln * 4);
            ax[d][0] += bf2f((u16)(pk.x & 0xffffu));
            ax[d][1] += bf2f((u16)(pk.x >> 16));
            ax[d][2] += bf2f((u16)(pk.y & 0xffffu));
            ax[d][3] += bf2f((u16)(pk.y >> 16));
        }
    }
    for (; q < rpe; ++q) {
        const int c = colidx[q];
        const uint2 pk = *reinterpret_cast<const uint2*>(
            rep_preh + (size_t)c * 256 + ln * 4);
        ax[0][0] += bf2f((u16)(pk.x & 0xffffu));
        ax[0][1] += bf2f((u16)(pk.x >> 16));
        ax[0][2] += bf2f((u16)(pk.y & 0xffffu));
        ax[0][3] += bf2f((u16)(pk.y >> 16));
    }

    const float* bsrc = (ln < 32) ? (gcB + ln * 4) : (gctB + (ln - 32) * 4);
    const float4 b4 = *reinterpret_cast<const float4*>(bsrc);
    float val[4];
    val[0] = fmaxf(((ax[0][0] + ax[1][0]) + (ax[2][0] + ax[3][0])) + b4.x, 0.f);
    val[1] = fmaxf(((ax[0][1] + ax[1][1]) + (ax[2][1] + ax[3][1])) + b4.y, 0.f);
    val[2] = fmaxf(((ax[0][2] + ax[1][2]) + (ax[2][2] + ax[3][2])) + b4.z, 0.f);
    val[3] = fmaxf(((ax[0][3] + ax[1][3]) + (ax[2][3] + ax[3][3])) + b4.w, 0.f);

    *reinterpret_cast<float4*>(rep + (size_t)i * 256 + ln * 4) =
        make_float4(val[0], val[1], val[2], val[3]);

    if (ln >= 32) {
        uint2 pk;
        pk.x = (unsigned int)f2bf(val[0]) | ((unsigned int)f2bf(val[1]) << 16);
        pk.y = (unsigned int)f2bf(val[2]) | ((unsigned int)f2bf(val[3]) << 16);
        *reinterpret_cast<uint2*>(rep_t_h + (size_t)i * 128 + (ln - 32) * 4) = pk;
        const int fb = (ln - 32) * 4;
        scs[w][fb + 0] = val[0];
        scs[w][fb + 1] = val[1];
        scs[w][fb + 2] = val[2];
        scs[w][fb + 3] = val[3];
    }

    // u,v butterfly (deterministic)
    const float4 av0 = *reinterpret_cast<const float4*>(avec + ln * 4);
    const float4 av1 = *reinterpret_cast<const float4*>(avec + 256 + ln * 4);
    float pu = av0.x * val[0] + av0.y * val[1] + av0.z * val[2] + av0.w * val[3];
    float pv = av1.x * val[0] + av1.y * val[1] + av1.z * val[2] + av1.w * val[3];
#pragma unroll
    for (int off = 32; off > 0; off >>= 1) {
        pu += __shfl_xor(pu, off, 64);
        pv += __shfl_xor(pv, off, 64);
    }
    if (ln == 0) { u[i] = pu; v[i] = pv; }

    __syncthreads();
    if (tid < 128)
        colpart[(size_t)b * 128 + tid] =
            (scs[0][tid] + scs[1][tid]) + (scs[2][tid] + scs[3][tid]);
}

// ============ K4: fold colsum partials 2048 -> 64 ===========================
__global__ __launch_bounds__(128)
void colsum_fold(const float* __restrict__ colpart, float* __restrict__ colpart2)
{
    const int f = threadIdx.x;
    const int b = blockIdx.x;          // 64 blocks x 32 partials
    float s0 = 0.f, s1 = 0.f, s2 = 0.f, s3 = 0.f;
    for (int j = 0; j < 32; j += 4) {
        s0 += colpart[(size_t)(b * 32 + j + 0) * 128 + f];
        s1 += colpart[(size_t)(b * 32 + j + 1) * 128 + f];
        s2 += colpart[(size_t)(b * 32 + j + 2) * 128 + f];
        s3 += colpart[(size_t)(b * 32 + j + 3) * 128 + f];
    }
    colpart2[(size_t)b * 128 + f] = (s0 + s1) + (s2 + s3);
}

// ====== K5a: attention only (wave-per-row, barrier-free) -> hp_out ==========
__global__ __launch_bounds__(256)
void attn_k(const int* __restrict__ rowptr,
            const int* __restrict__ colidx,
            const float* __restrict__ u,
            const float* __restrict__ v,
            const u16* __restrict__ rep_t_h,
            const float* __restrict__ rep,
            const float* __restrict__ colpart2,   // [64][128]
            float* __restrict__ hp_out)
{
    const int bid  = blockIdx.x;
    const int tid  = threadIdx.x;
    const int w    = tid >> 6, lane = tid & 63;
    const int f2   = lane * 2;

    __shared__ float wsh[4][128];
    __shared__ int   csh[4][128];

    // csum (2 feats per lane), fixed-order fold of 64 partials
    float cs0 = 0.f, cs1 = 0.f;
    for (int j = 0; j < 64; ++j) {
        const float2 cc = *reinterpret_cast<const float2*>(
            colpart2 + (size_t)j * 128 + f2);
        cs0 += cc.x; cs1 += cc.y;
    }

    for (int pr = 0; pr < 2; ++pr) {
        const int row = bid * 8 + pr * 4 + w;
        const int rp  = rowptr[row];
        const int deg = rowptr[row + 1] - rp;
        const float ui = u[row];

        // pass 1: max of v over neighbors (butterfly, no LDS)
        float mloc = -1e30f;
        for (int q = lane; q < deg; q += 64)
            mloc = fmaxf(mloc, v[colidx[rp + q]]);
#pragma unroll
        for (int off = 32; off > 0; off >>= 1)
            mloc = fmaxf(mloc, __shfl_xor(mloc, off, 64));
        const float m  = fmaxf(ui + mloc, 0.f);
        const float e0 = expf(-m);

        float Z = 0.f, acc0 = 0.f, acc1 = 0.f;
        for (int base = 0; base < deg; base += 128) {
            const int q1 = base + lane, q2 = base + 64 + lane;
            if (q1 < deg) {
                const int c = colidx[rp + q1];
                const float wv = expf(ui + v[c] - m);
                wsh[w][lane] = wv; csh[w][lane] = c;
                Z += wv;
            }
            if (q2 < deg) {
                const int c = colidx[rp + q2];
                const float wv = expf(ui + v[c] - m);
                wsh[w][64 + lane] = wv; csh[w][64 + lane] = c;
                Z += wv;
            }
            // same-wave LDS RAW: ordered by lgkmcnt, no barrier needed
            const int cnt2 = min(128, deg - base);
            float2 pa[8];
#pragma unroll
            for (int d = 0; d < 8; ++d) pa[d] = make_float2(0.f, 0.f);
            int q3 = 0;
            for (; q3 + 8 <= cnt2; q3 += 8) {
#pragma unroll
                for (int d = 0; d < 8; ++d) {
                    const float wv = wsh[w][q3 + d] - e0;
                    const unsigned int pk = *reinterpret_cast<const unsigned int*>(
                        rep_t_h + (size_t)csh[w][q3 + d] * 128 + f2);
                    pa[d].x += wv * bf2f((u16)(pk & 0xffffu));
                    pa[d].y += wv * bf2f((u16)(pk >> 16));
                }
            }
            for (; q3 < cnt2; ++q3) {
                const float wv = wsh[w][q3] - e0;
                const unsigned int pk = *reinterpret_cast<const unsigned int*>(
                    rep_t_h + (size_t)csh[w][q3] * 128 + f2);
                pa[0].x += wv * bf2f((u16)(pk & 0xffffu));
                pa[0].y += wv * bf2f((u16)(pk >> 16));
            }
            acc0 += ((pa[0].x + pa[1].x) + (pa[2].x + pa[3].x)) +
                    ((pa[4].x + pa[5].x) + (pa[6].x + pa[7].x));
            acc1 += ((pa[0].y + pa[1].y) + (pa[2].y + pa[3].y)) +
                    ((pa[4].y + pa[5].y) + (pa[6].y + pa[7].y));
        }
#pragma unroll
        for (int off = 32; off > 0; off >>= 1)
            Z += __shfl_xor(Z, off, 64);
        const float Zf = Z + (8192.f - (float)deg) * e0;

        const float2 rv = *reinterpret_cast<const float2*>(
            rep + (size_t)row * 256 + f2);
        const float hv0 = (acc0 + e0 * cs0) / Zf + rv.x;
        const float hv1 = (acc1 + e0 * cs1) / Zf + rv.y;
        *reinterpret_cast<float2*>(hp_out + (size_t)row * 128 + f2) =
            make_float2(hv0, hv1);
    }
}

// ====== K5b: output heads (standalone, float4-vectorized k-loop) ============
__global__ __launch_bounds__(256)
void heads_k(const float* __restrict__ hp,      // [N,128]
             const float* __restrict__ rep,     // [N,256]
             const int* __restrict__ t,
             const float* __restrict__ ppW,  const float* __restrict__ ppB,
             const float* __restrict__ pp2W, const float* __restrict__ pp2B,
             const float* __restrict__ t00W, const float* __restrict__ t00B,
             const float* __restrict__ t10W, const float* __restrict__ t10B,
             const float* __restrict__ t01W, const float* __restrict__ t01B,
             const float* __restrict__ t11W, const float* __restrict__ t11B,
             float* __restrict__ y_out,
             float* __restrict__ treat_out)
{
    const int bid  = blockIdx.x;
    const int tid  = threadIdx.x;
    const int h    = tid >> 7, f = tid & 127;
    const int lane = tid & 63;
    const int r0   = bid * 8;

    __shared__ __align__(16) float hs[8][128];
    __shared__ __align__(16) float ts[8][128];
    __shared__ float fin[2][2][4][4];

#pragma unroll
    for (int r = 0; r < 4; ++r) {
        hs[h * 4 + r][f] = hp[(size_t)(r0 + h * 4 + r) * 128 + f];
        ts[h * 4 + r][f] = rep[(size_t)(r0 + h * 4 + r) * 256 + 128 + f];
    }
    __syncthreads();

    float a00[4] = {0, 0, 0, 0}, a10[4] = {0, 0, 0, 0}, app[4] = {0, 0, 0, 0};
    for (int k = 0; k < 128; k += 4) {
        float4 hv4[4], tv4[4];
#pragma unroll
        for (int r = 0; r < 4; ++r) {
            hv4[r] = *reinterpret_cast<const float4*>(&hs[h * 4 + r][k]);
            tv4[r] = *reinterpret_cast<const float4*>(&ts[h * 4 + r][k]);
        }
#pragma unroll
        for (int j = 0; j < 4; ++j) {
            const float w00j = t00W[(k + j) * 128 + f];
            const float w10j = t10W[(k + j) * 128 + f];
            const float wppj = ppW [(k + j) * 128 + f];
#pragma unroll
            for (int r = 0; r < 4; ++r) {
                const float hj = (j == 0) ? hv4[r].x : (j == 1) ? hv4[r].y
                               : (j == 2) ? hv4[r].z : hv4[r].w;
                const float tj = (j == 0) ? tv4[r].x : (j == 1) ? tv4[r].y
                               : (j == 2) ? tv4[r].z : tv4[r].w;
                a00[r] += hj * w00j;
                a10[r] += hj * w10j;
                app[r] += tj * wppj;
            }
        }
    }
    const float b00 = t00B[f], b10 = t10B[f], bpp = ppB[f];
    const float w01 = t01W[f], w11 = t11W[f];
    const float w20 = pp2W[2 * f + 0], w21 = pp2W[2 * f + 1];
    const int wih = (tid >> 6) & 1;
#pragma unroll
    for (int r = 0; r < 4; ++r) {
        float s0 = fmaxf(a00[r] + b00, 0.f) * w01;
        float s1 = fmaxf(a10[r] + b10, 0.f) * w11;
        const float hp2 = app[r] + bpp;
        float s2 = hp2 * w20;
        float s3 = hp2 * w21;
#pragma unroll
        for (int off = 32; off > 0; off >>= 1) {
            s0 += __shfl_down(s0, off, 64);
            s1 += __shfl_down(s1, off, 64);
            s2 += __shfl_down(s2, off, 64);
            s3 += __shfl_down(s3, off, 64);
        }
        if (lane == 0) {
            fin[h][wih][r][0] = s0;
            fin[h][wih][r][1] = s1;
            fin[h][wih][r][2] = s2;
            fin[h][wih][r][3] = s3;
        }
    }
    __syncthreads();
    if (tid < 8) {
        const int hh = tid >> 2, rr = tid & 3;
        const int node = r0 + hh * 4 + rr;
        const float y0 = fin[hh][0][rr][0] + fin[hh][1][rr][0] + t01B[0];
        const float y1 = fin[hh][0][rr][1] + fin[hh][1][rr][1] + t11B[0];
        y_out[node] = (t[node] > 0) ? y1 : y0;
        const float tr0 = fin[hh][0][rr][2] + fin[hh][1][rr][2] + pp2B[0];
        const float tr1 = fin[hh][0][rr][3] + fin[hh][1][rr][3] + pp2B[1];
        treat_out[node * 2 + 0] = 1.f / (1.f + expf(-tr0));
        treat_out[node * 2 + 1] = 1.f / (1.f + expf(-tr1));
    }
}

// ===========================================================================
extern "C" void kernel_launch(void* const* d_in, const int* in_sizes, int n_in,
                              void* d_out, int out_size, void* d_ws, size_t ws_size,
                              hipStream_t stream)
{
    const float* x    = (const float*)d_in[0];
    // d_in[1] = dense adj : intentionally unused
    const int*   ei   = (const int*)d_in[2];
    const int*   t    = (const int*)d_in[3];
    const float* gcW  = (const float*)d_in[4];
    const float* gcB  = (const float*)d_in[5];
    const float* gctW = (const float*)d_in[6];
    const float* gctB = (const float*)d_in[7];
    const float* avec = (const float*)d_in[8];
    const float* ppW  = (const float*)d_in[9];
    const float* ppB  = (const float*)d_in[10];
    const float* pp2W = (const float*)d_in[11];
    const float* pp2B = (const float*)d_in[12];
    const float* t00W = (const float*)d_in[13];
    const float* t00B = (const float*)d_in[14];
    const float* t10W = (const float*)d_in[15];
    const float* t10B = (const float*)d_in[16];
    const float* t01W = (const float*)d_in[17];
    const float* t01B = (const float*)d_in[18];
    const float* t11W = (const float*)d_in[19];
    const float* t11B = (const float*)d_in[20];

    const int E = in_sizes[2] / 2;

    char* ws = (char*)d_ws;
    unsigned int* bitmap   = (unsigned int*)(ws + 0);
    int*          cnt      = (int*)   (ws + 8388608);
    u16*          rep_preh = (u16*)   (ws + 8421376);
    float*        rep      = (float*) (ws + 12615680);
    u16*          rep_t_h  = (u16*)   (ws + 21004288);
    float*        u        = (float*) (ws + 23101440);
    float*        v        = (float*) (ws + 23134208);
    int*          rowptr   = (int*)   (ws + 23166976);
    int*          colidx   = (int*)   (ws + 23200256);
    float*        colpart  = (float*) (ws + 24248832);
    float*        colpart2 = (float*) (ws + 25297408);

    float* y_out  = (float*)d_out;
    float* hp_out = (float*)d_out + N_NODES;
    float* tr_out = (float*)d_out + N_NODES + (size_t)N_NODES * NHID;

    const int n16 = (8388608 + 32768) / 16;   // bitmap+cnt in uint4s

    init_gemm<<<2560, 256, 0, stream>>>(x, gcW, gctW, rep_preh,
                                        (uint4*)ws, n16);
    edge_pass1<<<(E + 255) / 256, 256, 0, stream>>>(ei, E, bitmap, cnt);
    agg_all<<<2048, 256, 0, stream>>>(bitmap, cnt, rep_preh,
                                      gcB, gctB, avec,
                                      rowptr, colidx, rep, rep_t_h,
                                      u, v, colpart);
    colsum_fold<<<64, 128, 0, stream>>>(colpart, colpart2);
    attn_k<<<N_NODES / 8, 256, 0, stream>>>(rowptr, colidx, u, v,
                                            rep_t_h, rep, colpart2, hp_out);
    heads_k<<<N_NODES / 8, 256, 0, stream>>>(hp_out, rep, t,
                                             ppW, ppB, pp2W, pp2B,
                                             t00W, t00B, t10W, t10B,
                                             t01W, t01B, t11W, t11B,
                                             y_out, tr_out);
}

// Round 18
// 103.024 us; speedup vs baseline: 7.7948x; 7.7948x over previous
//
#include <hip/hip_runtime.h>
#include <cstdint>
#include <cstddef>

#define N_NODES 8192
#define NFEAT   512
#define NHID    128

typedef unsigned short u16;
typedef __attribute__((ext_vector_type(8))) short bf16x8;
typedef __attribute__((ext_vector_type(4))) float f32x4;

__device__ inline u16 f2bf(float f) {
    unsigned int u = __float_as_uint(f);
    unsigned int r = (u + 0x7FFFu + ((u >> 16) & 1u)) >> 16;
    return (u16)r;
}
__device__ inline float bf2f(u16 h) {
    return __uint_as_float(((unsigned int)h) << 16);
}

// ---------------------------------------------------------------------------
// FINAL = best-measured round-10/16 pipeline (103.2 us, reproduced twice).
// NOTE (regalloc): do NOT widen the heads k-loop with float4 LDS reads or
// restructure attention to register-cache (c,v) — both patterns push hipcc
// past the VGPR cliff (256 VGPR + ~1.2 GB scratch spill, 7-10x slowdown);
// measured rounds 14/15/17.
// Workspace layout (bytes):
//   [0]          bitmap    : 8388608   (zeroed by init_gemm blocks 512+)
//   [8388608]    cnt       : 32768     (zeroed)
//   [8421376]    rep_preh  : 4194304   (bf16 [N,256])
//   [12615680]   rep       : 8388608   (f32  [N,256])
//   [21004288]   rep_t_h   : 2097152   (bf16 [N,128])
//   [23101440]   u         : 32768
//   [23134208]   v         : 32768
//   [23166976]   rowptr    : 33280
//   [23200256]   colidx    : 1048576
//   [24248832]   colpart   : 2048*128*4 = 1048576
//   [25297408]   colpart2  : 64*128*4   = 32768
// ---------------------------------------------------------------------------

// ====== K1: blocks 0..511 GEMM (XCD-swizzled tiles), 512..2559 zero ws ======
__global__ __launch_bounds__(256)
void init_gemm(const float* __restrict__ x,
               const float* __restrict__ gcW,
               const float* __restrict__ gctW,
               u16* __restrict__ rep_preh,
               uint4* __restrict__ zdst, int n16)
{
    const int tid = threadIdx.x;
    if (blockIdx.x >= 512) {
        const uint4 z = make_uint4(0u, 0u, 0u, 0u);
        for (int i = (blockIdx.x - 512) * 256 + tid; i < n16; i += 2048 * 256)
            zdst[i] = z;
        return;
    }
    const int tile = (blockIdx.x & 7) * 64 + (blockIdx.x >> 3);  // XCD swizzle
    const int bx   = tile & 3;
    const int by   = tile >> 2;
    const int lane = tid & 63;
    const int wid  = tid >> 6;
    const int wr   = wid >> 1, wc = wid & 1;
    const float* W = (bx < 2) ? gcW : gctW;
    const int n0w  = (bx & 1) * 64;
    const int row0 = by * 64;

    __shared__ __align__(16) u16 Ash[64][40];
    __shared__ __align__(16) u16 Bsh[64][40];

    f32x4 acc[2][2];
#pragma unroll
    for (int i = 0; i < 2; ++i)
#pragma unroll
        for (int j = 0; j < 2; ++j) acc[i][j] = (f32x4){0.f, 0.f, 0.f, 0.f};

    const int sr = tid >> 2;
    const int sq = tid & 3;
    const int fr = lane & 15;
    const int fq = lane >> 4;

    for (int k0 = 0; k0 < NFEAT; k0 += 32) {
        {
            const float* src = x + (size_t)(row0 + sr) * NFEAT + k0 + sq * 8;
            const float4 a0 = *reinterpret_cast<const float4*>(src);
            const float4 a1 = *reinterpret_cast<const float4*>(src + 4);
            union { u16 s[8]; bf16x8 v; } pk;
            pk.s[0] = f2bf(a0.x); pk.s[1] = f2bf(a0.y);
            pk.s[2] = f2bf(a0.z); pk.s[3] = f2bf(a0.w);
            pk.s[4] = f2bf(a1.x); pk.s[5] = f2bf(a1.y);
            pk.s[6] = f2bf(a1.z); pk.s[7] = f2bf(a1.w);
            *reinterpret_cast<bf16x8*>(&Ash[sr][sq * 8]) = pk.v;
        }
        {
            const float* wsrc = W + (size_t)(k0 + sq * 8) * NHID + n0w + sr;
            union { u16 s[8]; bf16x8 v; } pk;
#pragma unroll
            for (int j = 0; j < 8; ++j)
                pk.s[j] = f2bf(wsrc[(size_t)j * NHID]);
            *reinterpret_cast<bf16x8*>(&Bsh[sr][sq * 8]) = pk.v;
        }
        __syncthreads();
        const bf16x8 a0 = *reinterpret_cast<const bf16x8*>(&Ash[wr * 32 + fr][fq * 8]);
        const bf16x8 a1 = *reinterpret_cast<const bf16x8*>(&Ash[wr * 32 + 16 + fr][fq * 8]);
        const bf16x8 b0 = *reinterpret_cast<const bf16x8*>(&Bsh[wc * 32 + fr][fq * 8]);
        const bf16x8 b1 = *reinterpret_cast<const bf16x8*>(&Bsh[wc * 32 + 16 + fr][fq * 8]);
        acc[0][0] = __builtin_amdgcn_mfma_f32_16x16x32_bf16(a0, b0, acc[0][0], 0, 0, 0);
        acc[0][1] = __builtin_amdgcn_mfma_f32_16x16x32_bf16(a0, b1, acc[0][1], 0, 0, 0);
        acc[1][0] = __builtin_amdgcn_mfma_f32_16x16x32_bf16(a1, b0, acc[1][0], 0, 0, 0);
        acc[1][1] = __builtin_amdgcn_mfma_f32_16x16x32_bf16(a1, b1, acc[1][1], 0, 0, 0);
        __syncthreads();
    }
    const int gr = row0 + wr * 32 + fq * 4;
    const int gc = bx * 64 + wc * 32 + fr;
#pragma unroll
    for (int mi = 0; mi < 2; ++mi)
#pragma unroll
        for (int ni = 0; ni < 2; ++ni)
#pragma unroll
            for (int i = 0; i < 4; ++i)
                rep_preh[(size_t)(gr + mi * 16 + i) * 256 + gc + ni * 16] =
                    f2bf(acc[mi][ni][i]);
}

// ============ K2: edge dedup (bitmap ownership + row counts) ================
__global__ void edge_pass1(const int* __restrict__ ei, int E,
                           unsigned int* __restrict__ bitmap,
                           int* __restrict__ cnt)
{
    const int e = blockIdx.x * blockDim.x + threadIdx.x;
    if (e >= E) return;
    const int s = ei[e];
    const int d = ei[E + e];
    const unsigned int idx  = (unsigned int)s * 8192u + (unsigned int)d;
    const unsigned int mask = 1u << (idx & 31u);
    const unsigned int old  = atomicOr(&bitmap[idx >> 5], mask);
    if ((old & mask) == 0u) atomicAdd(&cnt[s], 1);  // int add: deterministic
}

// ====== K3: fused {base-offset, extract, aggregate, u/v, colsum partials}
//        2048 blocks x 256 thr; wave w owns row 4b+w; lane owns 4 feats. ====
__global__ __launch_bounds__(256)
void agg_all(const unsigned int* __restrict__ bitmap,
             const int* __restrict__ cnt,
             const u16* __restrict__ rep_preh,
             const float* __restrict__ gcB,
             const float* __restrict__ gctB,
             const float* __restrict__ avec,
             int* __restrict__ rowptr,
             int* __restrict__ colidx,
             float* __restrict__ rep,
             u16* __restrict__ rep_t_h,
             float* __restrict__ u,
             float* __restrict__ v,
             float* __restrict__ colpart)   // [2048][128]
{
    const int b   = blockIdx.x;
    const int tid = threadIdx.x;
    const int w   = tid >> 6, ln = tid & 63;
    const int R0  = b * 4;

    __shared__ int   red_i[256];
    __shared__ int   rowoff[5];
    __shared__ float scs[4][128];

    // ---- base offset = sum cnt[0 .. R0) ------------------------------------
    {
        int ssum = 0;
        const int cb = tid * 32;
        if (cb + 32 <= R0) {
#pragma unroll
            for (int j = 0; j < 32; ++j) ssum += cnt[cb + j];
        } else if (cb < R0) {
            const int lim = R0 - cb;
            for (int j = 0; j < lim; ++j) ssum += cnt[cb + j];
        }
        red_i[tid] = ssum;
        __syncthreads();
#pragma unroll
        for (int s = 128; s > 0; s >>= 1) {
            if (tid < s) red_i[tid] += red_i[tid + s];
            __syncthreads();
        }
        if (tid == 0) {
            int off = red_i[0];
            for (int j = 0; j < 4; ++j) {
                rowoff[j] = off;
                rowptr[R0 + j] = off;
                off += cnt[R0 + j];
            }
            rowoff[4] = off;
            if (b == 2047) rowptr[N_NODES] = off;
        }
        __syncthreads();
    }

    // ---- extract sorted cols: wave w does row R0+w -------------------------
    {
        const int row = R0 + w;
        const uint4 w4 = *reinterpret_cast<const uint4*>(
            bitmap + (size_t)row * 256 + ln * 4);
        const int c = __popc(w4.x) + __popc(w4.y) + __popc(w4.z) + __popc(w4.w);
        int off = c;
        for (int d = 1; d < 64; d <<= 1) {
            const int n = __shfl_up(off, d, 64);
            if (ln >= d) off += n;
        }
        off -= c;
        int pos = rowoff[w] + off;
        const int base = ln * 128;
        unsigned int wvv[4] = {w4.x, w4.y, w4.z, w4.w};
#pragma unroll
        for (int j = 0; j < 4; ++j) {
            unsigned int bb = wvv[j];
            while (bb) {
                const int bit = __ffs(bb) - 1;
                colidx[pos++] = base + j * 32 + bit;
                bb &= bb - 1;
            }
        }
    }
    __syncthreads();

    // ---- aggregate row R0+w: lane ln owns feats ln*4..ln*4+3 ---------------
    const int i   = R0 + w;
    const int rp  = rowoff[w];
    const int rpe = rowoff[w + 1];

    float ax[4][4];
#pragma unroll
    for (int d = 0; d < 4; ++d)
#pragma unroll
        for (int j = 0; j < 4; ++j) ax[d][j] = 0.f;

    int q = rp;
    for (; q + 4 <= rpe; q += 4) {
#pragma unroll
        for (int d = 0; d < 4; ++d) {
            const int c = colidx[q + d];
            const uint2 pk = *reinterpret_cast<const uint2*>(
                rep_preh + (size_t)c * 256 + ln * 4);
            ax[d][0] += bf2f((u16)(pk.x & 0xffffu));
            ax[d][1] += bf2f((u16)(pk.x >> 16));
            ax[d][2] += bf2f((u16)(pk.y & 0xffffu));
            ax[d][3] += bf2f((u16)(pk.y >> 16));
        }
    }
    for (; q < rpe; ++q) {
        const int c = colidx[q];
        const uint2 pk = *reinterpret_cast<const uint2*>(
            rep_preh + (size_t)c * 256 + ln * 4);
        ax[0][0] += bf2f((u16)(pk.x & 0xffffu));
        ax[0][1] += bf2f((u16)(pk.x >> 16));
        ax[0][2] += bf2f((u16)(pk.y & 0xffffu));
        ax[0][3] += bf2f((u16)(pk.y >> 16));
    }

    const float* bsrc = (ln < 32) ? (gcB + ln * 4) : (gctB + (ln - 32) * 4);
    const float4 b4 = *reinterpret_cast<const float4*>(bsrc);
    float val[4];
    val[0] = fmaxf(((ax[0][0] + ax[1][0]) + (ax[2][0] + ax[3][0])) + b4.x, 0.f);
    val[1] = fmaxf(((ax[0][1] + ax[1][1]) + (ax[2][1] + ax[3][1])) + b4.y, 0.f);
    val[2] = fmaxf(((ax[0][2] + ax[1][2]) + (ax[2][2] + ax[3][2])) + b4.z, 0.f);
    val[3] = fmaxf(((ax[0][3] + ax[1][3]) + (ax[2][3] + ax[3][3])) + b4.w, 0.f);

    *reinterpret_cast<float4*>(rep + (size_t)i * 256 + ln * 4) =
        make_float4(val[0], val[1], val[2], val[3]);

    if (ln >= 32) {
        uint2 pk;
        pk.x = (unsigned int)f2bf(val[0]) | ((unsigned int)f2bf(val[1]) << 16);
        pk.y = (unsigned int)f2bf(val[2]) | ((unsigned int)f2bf(val[3]) << 16);
        *reinterpret_cast<uint2*>(rep_t_h + (size_t)i * 128 + (ln - 32) * 4) = pk;
        const int fb = (ln - 32) * 4;
        scs[w][fb + 0] = val[0];
        scs[w][fb + 1] = val[1];
        scs[w][fb + 2] = val[2];
        scs[w][fb + 3] = val[3];
    }

    // u,v butterfly (deterministic)
    const float4 av0 = *reinterpret_cast<const float4*>(avec + ln * 4);
    const float4 av1 = *reinterpret_cast<const float4*>(avec + 256 + ln * 4);
    float pu = av0.x * val[0] + av0.y * val[1] + av0.z * val[2] + av0.w * val[3];
    float pv = av1.x * val[0] + av1.y * val[1] + av1.z * val[2] + av1.w * val[3];
#pragma unroll
    for (int off = 32; off > 0; off >>= 1) {
        pu += __shfl_xor(pu, off, 64);
        pv += __shfl_xor(pv, off, 64);
    }
    if (ln == 0) { u[i] = pu; v[i] = pv; }

    __syncthreads();
    if (tid < 128)
        colpart[(size_t)b * 128 + tid] =
            (scs[0][tid] + scs[1][tid]) + (scs[2][tid] + scs[3][tid]);
}

// ============ K4: fold colsum partials 2048 -> 64 ===========================
__global__ __launch_bounds__(128)
void colsum_fold(const float* __restrict__ colpart, float* __restrict__ colpart2)
{
    const int f = threadIdx.x;
    const int b = blockIdx.x;          // 64 blocks x 32 partials
    float s0 = 0.f, s1 = 0.f, s2 = 0.f, s3 = 0.f;
    for (int j = 0; j < 32; j += 4) {
        s0 += colpart[(size_t)(b * 32 + j + 0) * 128 + f];
        s1 += colpart[(size_t)(b * 32 + j + 1) * 128 + f];
        s2 += colpart[(size_t)(b * 32 + j + 2) * 128 + f];
        s3 += colpart[(size_t)(b * 32 + j + 3) * 128 + f];
    }
    colpart2[(size_t)b * 128 + f] = (s0 + s1) + (s2 + s3);
}

// ====== K5: attention (wave-per-row, barrier-free row loop) + heads =========
__global__ __launch_bounds__(256)
void attn_heads(const int* __restrict__ rowptr,
                const int* __restrict__ colidx,
                const float* __restrict__ u,
                const float* __restrict__ v,
                const u16* __restrict__ rep_t_h,
                const float* __restrict__ rep,
                const float* __restrict__ colpart2,   // [64][128]
                const int* __restrict__ t,
                const float* __restrict__ ppW,  const float* __restrict__ ppB,
                const float* __restrict__ pp2W, const float* __restrict__ pp2B,
                const float* __restrict__ t00W, const float* __restrict__ t00B,
                const float* __restrict__ t10W, const float* __restrict__ t10B,
                const float* __restrict__ t01W, const float* __restrict__ t01B,
                const float* __restrict__ t11W, const float* __restrict__ t11B,
                float* __restrict__ y_out,
                float* __restrict__ hp_out,
                float* __restrict__ tr_out)
{
    const int bid  = blockIdx.x;
    const int tid  = threadIdx.x;
    const int w    = tid >> 6, lane = tid & 63;
    const int f2   = lane * 2;

    __shared__ float wsh[4][128];
    __shared__ int   csh[4][128];
    __shared__ float hs[8][128];
    __shared__ float ts[8][128];
    __shared__ float fin[2][2][4][4];

    // csum (2 feats per lane), fixed-order fold of 64 partials
    float cs0 = 0.f, cs1 = 0.f;
    for (int j = 0; j < 64; ++j) {
        const float2 cc = *reinterpret_cast<const float2*>(
            colpart2 + (size_t)j * 128 + f2);
        cs0 += cc.x; cs1 += cc.y;
    }

    for (int pr = 0; pr < 2; ++pr) {
        const int row = bid * 8 + pr * 4 + w;
        const int rp  = rowptr[row];
        const int deg = rowptr[row + 1] - rp;
        const float ui = u[row];

        // pass 1: max of v over neighbors (butterfly, no LDS)
        float mloc = -1e30f;
        for (int q = lane; q < deg; q += 64)
            mloc = fmaxf(mloc, v[colidx[rp + q]]);
#pragma unroll
        for (int off = 32; off > 0; off >>= 1)
            mloc = fmaxf(mloc, __shfl_xor(mloc, off, 64));
        const float m  = fmaxf(ui + mloc, 0.f);
        const float e0 = expf(-m);

        float Z = 0.f, acc0 = 0.f, acc1 = 0.f;
        for (int base = 0; base < deg; base += 128) {
            const int q1 = base + lane, q2 = base + 64 + lane;
            if (q1 < deg) {
                const int c = colidx[rp + q1];
                const float wv = expf(ui + v[c] - m);
                wsh[w][lane] = wv; csh[w][lane] = c;
                Z += wv;
            }
            if (q2 < deg) {
                const int c = colidx[rp + q2];
                const float wv = expf(ui + v[c] - m);
                wsh[w][64 + lane] = wv; csh[w][64 + lane] = c;
                Z += wv;
            }
            // same-wave LDS RAW: ordered by lgkmcnt, no barrier needed
            const int cnt2 = min(128, deg - base);
            float2 pa[8];
#pragma unroll
            for (int d = 0; d < 8; ++d) pa[d] = make_float2(0.f, 0.f);
            int q3 = 0;
            for (; q3 + 8 <= cnt2; q3 += 8) {
#pragma unroll
                for (int d = 0; d < 8; ++d) {
                    const float wv = wsh[w][q3 + d] - e0;
                    const unsigned int pk = *reinterpret_cast<const unsigned int*>(
                        rep_t_h + (size_t)csh[w][q3 + d] * 128 + f2);
                    pa[d].x += wv * bf2f((u16)(pk & 0xffffu));
                    pa[d].y += wv * bf2f((u16)(pk >> 16));
                }
            }
            for (; q3 < cnt2; ++q3) {
                const float wv = wsh[w][q3] - e0;
                const unsigned int pk = *reinterpret_cast<const unsigned int*>(
                    rep_t_h + (size_t)csh[w][q3] * 128 + f2);
                pa[0].x += wv * bf2f((u16)(pk & 0xffffu));
                pa[0].y += wv * bf2f((u16)(pk >> 16));
            }
            acc0 += ((pa[0].x + pa[1].x) + (pa[2].x + pa[3].x)) +
                    ((pa[4].x + pa[5].x) + (pa[6].x + pa[7].x));
            acc1 += ((pa[0].y + pa[1].y) + (pa[2].y + pa[3].y)) +
                    ((pa[4].y + pa[5].y) + (pa[6].y + pa[7].y));
        }
#pragma unroll
        for (int off = 32; off > 0; off >>= 1)
            Z += __shfl_xor(Z, off, 64);
        const float Zf = Z + (8192.f - (float)deg) * e0;

        const float2 rv = *reinterpret_cast<const float2*>(
            rep + (size_t)row * 256 + f2);
        const float hv0 = (acc0 + e0 * cs0) / Zf + rv.x;
        const float hv1 = (acc1 + e0 * cs1) / Zf + rv.y;
        *reinterpret_cast<float2*>(hp_out + (size_t)row * 128 + f2) =
            make_float2(hv0, hv1);
        hs[pr * 4 + w][f2]     = hv0;
        hs[pr * 4 + w][f2 + 1] = hv1;
    }

    // ---------------- fused heads -------------------------------------------
    const int h = tid >> 7, f = tid & 127;
    const int r0 = bid * 8;
#pragma unroll
    for (int r = 0; r < 4; ++r)
        ts[h * 4 + r][f] = rep[(size_t)(r0 + h * 4 + r) * 256 + 128 + f];
    __syncthreads();

    float a00[4] = {0, 0, 0, 0}, a10[4] = {0, 0, 0, 0}, app[4] = {0, 0, 0, 0};
    for (int k = 0; k < 128; ++k) {
        const float w00 = t00W[k * 128 + f];
        const float w10 = t10W[k * 128 + f];
        const float wpp = ppW [k * 128 + f];
#pragma unroll
        for (int r = 0; r < 4; ++r) {
            a00[r] += hs[h * 4 + r][k] * w00;
            a10[r] += hs[h * 4 + r][k] * w10;
            app[r] += ts[h * 4 + r][k] * wpp;
        }
    }
    const float b00 = t00B[f], b10 = t10B[f], bpp = ppB[f];
    const float w01 = t01W[f], w11 = t11W[f];
    const float w20 = pp2W[2 * f + 0], w21 = pp2W[2 * f + 1];
    const int wih = (tid >> 6) & 1;
#pragma unroll
    for (int r = 0; r < 4; ++r) {
        float s0 = fmaxf(a00[r] + b00, 0.f) * w01;
        float s1 = fmaxf(a10[r] + b10, 0.f) * w11;
        const float hp2 = app[r] + bpp;
        float s2 = hp2 * w20;
        float s3 = hp2 * w21;
#pragma unroll
        for (int off = 32; off > 0; off >>= 1) {
            s0 += __shfl_down(s0, off, 64);
            s1 += __shfl_down(s1, off, 64);
            s2 += __shfl_down(s2, off, 64);
            s3 += __shfl_down(s3, off, 64);
        }
        if (lane == 0) {
            fin[h][wih][r][0] = s0;
            fin[h][wih][r][1] = s1;
            fin[h][wih][r][2] = s2;
            fin[h][wih][r][3] = s3;
        }
    }
    __syncthreads();
    if (tid < 8) {
        const int hh = tid >> 2, rr = tid & 3;
        const int node = r0 + hh * 4 + rr;
        const float y0 = fin[hh][0][rr][0] + fin[hh][1][rr][0] + t01B[0];
        const float y1 = fin[hh][0][rr][1] + fin[hh][1][rr][1] + t11B[0];
        y_out[node] = (t[node] > 0) ? y1 : y0;
        const float tr0 = fin[hh][0][rr][2] + fin[hh][1][rr][2] + pp2B[0];
        const float tr1 = fin[hh][0][rr][3] + fin[hh][1][rr][3] + pp2B[1];
        tr_out[node * 2 + 0] = 1.f / (1.f + expf(-tr0));
        tr_out[node * 2 + 1] = 1.f / (1.f + expf(-tr1));
    }
}

// ===========================================================================
extern "C" void kernel_launch(void* const* d_in, const int* in_sizes, int n_in,
                              void* d_out, int out_size, void* d_ws, size_t ws_size,
                              hipStream_t stream)
{
    const float* x    = (const float*)d_in[0];
    // d_in[1] = dense adj : intentionally unused
    const int*   ei   = (const int*)d_in[2];
    const int*   t    = (const int*)d_in[3];
    const float* gcW  = (const float*)d_in[4];
    const float* gcB  = (const float*)d_in[5];
    const float* gctW = (const float*)d_in[6];
    const float* gctB = (const float*)d_in[7];
    const float* avec = (const float*)d_in[8];
    const float* ppW  = (const float*)d_in[9];
    const float* ppB  = (const float*)d_in[10];
    const float* pp2W = (const float*)d_in[11];
    const float* pp2B = (const float*)d_in[12];
    const float* t00W = (const float*)d_in[13];
    const float* t00B = (const float*)d_in[14];
    const float* t10W = (const float*)d_in[15];
    const float* t10B = (const float*)d_in[16];
    const float* t01W = (const float*)d_in[17];
    const float* t01B = (const float*)d_in[18];
    const float* t11W = (const float*)d_in[19];
    const float* t11B = (const float*)d_in[20];

    const int E = in_sizes[2] / 2;

    char* ws = (char*)d_ws;
    unsigned int* bitmap   = (unsigned int*)(ws + 0);
    int*          cnt      = (int*)   (ws + 8388608);
    u16*          rep_preh = (u16*)   (ws + 8421376);
    float*        rep      = (float*) (ws + 12615680);
    u16*          rep_t_h  = (u16*)   (ws + 21004288);
    float*        u        = (float*) (ws + 23101440);
    float*        v        = (float*) (ws + 23134208);
    int*          rowptr   = (int*)   (ws + 23166976);
    int*          colidx   = (int*)   (ws + 23200256);
    float*        colpart  = (float*) (ws + 24248832);
    float*        colpart2 = (float*) (ws + 25297408);

    float* y_out  = (float*)d_out;
    float* hp_out = (float*)d_out + N_NODES;
    float* tr_out = (float*)d_out + N_NODES + (size_t)N_NODES * NHID;

    const int n16 = (8388608 + 32768) / 16;   // bitmap+cnt in uint4s

    init_gemm<<<2560, 256, 0, stream>>>(x, gcW, gctW, rep_preh,
                                        (uint4*)ws, n16);
    edge_pass1<<<(E + 255) / 256, 256, 0, stream>>>(ei, E, bitmap, cnt);
    agg_all<<<2048, 256, 0, stream>>>(bitmap, cnt, rep_preh,
                                      gcB, gctB, avec,
                                      rowptr, colidx, rep, rep_t_h,
                                      u, v, colpart);
    colsum_fold<<<64, 128, 0, stream>>>(colpart, colpart2);
    attn_heads<<<N_NODES / 8, 256, 0, stream>>>(rowptr, colidx, u, v,
                                                rep_t_h, rep, colpart2, t,
                                                ppW, ppB, pp2W, pp2B,
                                                t00W, t00B, t10W, t10B,
                                                t01W, t01B, t11W, t11B,
                                                y_out, hp_out, tr_out);
}